// Round 3
// baseline (192.515 us; speedup 1.0000x reference)
//
#include <hip/hip_runtime.h>

// SpatioConvLayer: B=16, C_IN=C_OUT=64, T=12, N=1024, KS=3
#define NB   16
#define NC   64
#define NT   12
#define NN   1024
#define NKS  3

typedef float  f32x4  __attribute__((ext_vector_type(4)));
typedef short  s16x8  __attribute__((ext_vector_type(8)));
typedef unsigned short u16x4 __attribute__((ext_vector_type(4)));
typedef unsigned short u16x8 __attribute__((ext_vector_type(8)));
typedef unsigned short ush;

__device__ __forceinline__ ush f2bf(float f) {
    union { float f; unsigned u; } v; v.f = f;
    unsigned r = v.u + 0x7FFFu + ((v.u >> 16) & 1u);   // RNE
    return (ush)(r >> 16);
}

// Workspace layout (frag-ordered panels: chunk id -> 16 B, perfectly coalesced
// per-wave fragment loads, no LDS staging needed in the K-loop):
//   apan @ 0        : bf16 A-frags [g2=96][kt=16][fidA=16][lane=64] x 16B  (25,165,824 B)
//                     fidA = wr*8 + rb*2 + kk ; lane=(quad,l16):
//                     element A[row=64wr+16rb+l16][k=kt*64+(kk*4+quad)*8 + i]
//   kb   @ 25165824 : bf16 B-frags [mt=16][kt=16][fidB=24][lane=64] x 16B  (6,291,456 B)
//                     fidB = wn*12 + kk*6 + jb ; element
//                     B[j=96wn+16jb+l16][k=kt*64+(kk*4+quad)*8 + i], B[j][n]=kern[n][col(j)]
//   thbf @ 31457280 : bf16 theta^T [o=64][ck=192]                          (24,576 B)
#define APAN_OFF 0
#define KB_OFF   25165824
#define TH_OFF   31457280

// ---------------- prep: convert + transpose into fragment order ----------------
// Block map: [0,6144) A-frags, [6144,6528) B-frags (coalesced transpose),
//            [6528,6576) theta.
__global__ __launch_bounds__(256)
void spatio_prep(const float* __restrict__ x, const float* __restrict__ kern,
                 const float* __restrict__ theta,
                 ush* __restrict__ apan, ush* __restrict__ kb, ush* __restrict__ thbf)
{
    const int blk = blockIdx.x;
    const int tid = threadIdx.x;

    if (blk < 6144) {
        // ---- A frags: one 16-B chunk per thread (linear writes, 128-B-coalesced reads) ----
        int id   = blk * 256 + tid;           // ((g2*16+kt)*16+fid)*64 + lane
        int lane = id & 63;
        int fid  = (id >> 6) & 15;
        int kt   = (id >> 10) & 15;
        int g2   = id >> 14;
        int quad = lane >> 4, l16 = lane & 15;
        int wr = fid >> 3, rb = (fid >> 1) & 3, kk = fid & 1;
        int row = 64 * wr + 16 * rb + l16;
        int c = row & 63, bl = row >> 6;
        int bt = 2 * g2 + bl;
        int b = bt / NT, t = bt - NT * b;
        int koff = kt * 64 + (kk * 4 + quad) * 8;
        const float* src = x + ((size_t)((b * NC + c) * NT + t)) * NN + koff;
        float4 a0 = ((const float4*)src)[0];
        float4 a1 = ((const float4*)src)[1];
        u16x8 w;
        w[0] = f2bf(a0.x); w[1] = f2bf(a0.y); w[2] = f2bf(a0.z); w[3] = f2bf(a0.w);
        w[4] = f2bf(a1.x); w[5] = f2bf(a1.y); w[6] = f2bf(a1.z); w[7] = f2bf(a1.w);
        ((u16x8*)apan)[id] = w;
    } else if (blk < 6528) {
        // ---- B frags: coalesced transpose ----
        // thread = (mt,kt,wn,kk,jb,l16g,quad): reads 8 float4 (4 cols x 8 rows of kern;
        // wave covers 4 fully-consumed 256-B row segments), writes 4 lanes' chunks (64 B).
        int id   = (blk - 6144) * 256 + tid;  // 0..98303
        int quad = id & 3;
        int l16g = (id >> 2) & 3;
        int rest = id >> 4;                   // (((mt*16+kt)*2+wn)*2+kk)*6 + jb
        int jb   = rest % 6;
        int r2   = rest / 6;
        int kk   = r2 & 1;
        int wn   = (r2 >> 1) & 1;
        int kt   = (r2 >> 2) & 15;
        int mt   = r2 >> 6;
        int j0   = 96 * wn + 16 * jb + 4 * l16g;
        int k    = j0 >> 6, mm0 = j0 & 63;
        int col0 = (k << 10) + (mt << 6) + mm0;
        int nbase = kt * 64 + (kk * 4 + quad) * 8;
        float4 v[8];
#pragma unroll
        for (int i = 0; i < 8; ++i)
            v[i] = *(const float4*)&kern[(size_t)(nbase + i) * (NKS * NN) + col0];
        int fid = wn * 12 + kk * 6 + jb;
        int cb  = ((mt * 16 + kt) * 24 + fid) * 64 + quad * 16 + 4 * l16g;
#pragma unroll
        for (int jj = 0; jj < 4; ++jj) {
            u16x8 w;
            w[0] = f2bf(v[0][jj]); w[1] = f2bf(v[1][jj]);
            w[2] = f2bf(v[2][jj]); w[3] = f2bf(v[3][jj]);
            w[4] = f2bf(v[4][jj]); w[5] = f2bf(v[5][jj]);
            w[6] = f2bf(v[6][jj]); w[7] = f2bf(v[7][jj]);
            ((u16x8*)kb)[cb + jj] = w;
        }
    } else {
        // ---- theta^T: thbf[o][k*64+c] ----
        int id = (blk - 6528) * 256 + tid;
        if (id < 12288) {
            int row = id >> 6, o = id & 63;   // row = c*3 + k
            int c = row / 3, k = row - 3 * c;
            thbf[o * 192 + k * 64 + c] = f2bf(theta[id]);
        }
    }
}

// ---------------- main: 128x192 tile, register-resident K-loop (no LDS staging) ----------------
// 4 waves (2 bt-halves x 2 col-halves), per-wave 64x96 = 4x6 fragments.
// Stage 1: global->reg fragment loads, software-pipelined one half-K-step ahead,
//          ZERO barriers. LDS only for stage-2 xm (25.6 KB).
__global__ __launch_bounds__(256, 2)
void spatio_main(const ush* __restrict__ apan, const ush* __restrict__ kb,
                 const ush* __restrict__ thbf, const float* __restrict__ bias,
                 const float* __restrict__ x, float* __restrict__ out)
{
    __shared__ __attribute__((aligned(128))) char smem[25600];
    ush (*xm)[200] = (ush (*)[200])smem;     // [mm][ck] stage-2 operand

    const int tid  = threadIdx.x;
    const int g2   = blockIdx.x;          // bt-pair 0..95 (g2%8 -> fixed XCD: A panel XCD-local)
    const int mt   = blockIdx.y;          // m-tile 0..15
    const int m_base = mt * 64;
    const int lane = tid & 63;
    const int wid  = tid >> 6;            // 0..3
    const int wr   = wid & 1;             // bt half (64 rows)
    const int wn   = wid >> 1;            // col half (96 j)
    const int quad = lane >> 4;
    const int l16  = lane & 15;

    const ush* Abp = apan + (size_t)g2 * 131072 + wr * 4096 + lane * 8;
    const ush* Bbp = kb   + (size_t)mt * 196608 + wn * 6144 + lane * 8;

    f32x4 acc[4][6];
#pragma unroll
    for (int i = 0; i < 4; ++i)
#pragma unroll
        for (int j = 0; j < 6; ++j) acc[i][j] = (f32x4){0.f, 0.f, 0.f, 0.f};

    // ===== stage 1: register-pipelined K-loop; half-step = (kt, kk), 24 MFMA each =====
    s16x8 Pa[4], Pb[6], Qa[4], Qb[6];
#pragma unroll
    for (int rb = 0; rb < 4; ++rb) Pa[rb] = *(const s16x8*)(Abp + (rb * 2 + 0) * 512);
#pragma unroll
    for (int jb = 0; jb < 6; ++jb) Pb[jb] = *(const s16x8*)(Bbp + (0 * 6 + jb) * 512);

    for (int h = 0; h < 32; h += 2) {
        const int kt = h >> 1;
        // prefetch half-step h+1 (same kt, kk=1) into Q
#pragma unroll
        for (int rb = 0; rb < 4; ++rb)
            Qa[rb] = *(const s16x8*)(Abp + kt * 8192 + (rb * 2 + 1) * 512);
#pragma unroll
        for (int jb = 0; jb < 6; ++jb)
            Qb[jb] = *(const s16x8*)(Bbp + kt * 12288 + (6 + jb) * 512);
        // compute half-step h on P
#pragma unroll
        for (int rb = 0; rb < 4; ++rb)
#pragma unroll
            for (int jb = 0; jb < 6; ++jb)
                acc[rb][jb] = __builtin_amdgcn_mfma_f32_16x16x32_bf16(Pa[rb], Pb[jb], acc[rb][jb], 0, 0, 0);
        // prefetch half-step h+2 (kt+1, kk=0) into P
        if (h + 2 < 32) {
#pragma unroll
            for (int rb = 0; rb < 4; ++rb)
                Pa[rb] = *(const s16x8*)(Abp + (kt + 1) * 8192 + (rb * 2) * 512);
#pragma unroll
            for (int jb = 0; jb < 6; ++jb)
                Pb[jb] = *(const s16x8*)(Bbp + (kt + 1) * 12288 + jb * 512);
        }
        // compute half-step h+1 on Q
#pragma unroll
        for (int rb = 0; rb < 4; ++rb)
#pragma unroll
            for (int jb = 0; jb < 6; ++jb)
                acc[rb][jb] = __builtin_amdgcn_mfma_f32_16x16x32_bf16(Qa[rb], Qb[jb], acc[rb][jb], 0, 0, 0);
    }

    // ===== stage 2: gc = th^T @ xm ; one bt per pass =====
    float bo[4];
#pragma unroll
    for (int r = 0; r < 4; ++r) bo[r] = bias[16 * wid + 4 * quad + r];

    for (int pass = 0; pass < 2; ++pass) {
        __syncthreads();               // previous-pass xm readers done
        if (wr == pass) {
            // write acc -> xm[mm][k*64+c] (B-operand layout)
#pragma unroll
            for (int rb = 0; rb < 4; ++rb)
#pragma unroll
                for (int jb = 0; jb < 6; ++jb) {
                    int J  = 96 * wn + 16 * jb + l16;
                    int kk = J >> 6, mm = J & 63;
                    int ck0 = kk * 64 + 16 * rb + 4 * quad;
                    u16x4 w;
                    w.x = f2bf(acc[rb][jb].x); w.y = f2bf(acc[rb][jb].y);
                    w.z = f2bf(acc[rb][jb].z); w.w = f2bf(acc[rb][jb].w);
                    *(u16x4*)&xm[mm][ck0] = w;
                }
        }
        __syncthreads();

        f32x4 acc2[4];
#pragma unroll
        for (int jb = 0; jb < 4; ++jb) acc2[jb] = (f32x4){0.f, 0.f, 0.f, 0.f};
#pragma unroll
        for (int ks = 0; ks < 6; ++ks) {       // K = 192
            s16x8 a2 = *(const s16x8*)(thbf + (size_t)(16 * wid + l16) * 192 + ks * 32 + quad * 8);
#pragma unroll
            for (int jb = 0; jb < 4; ++jb) {
                s16x8 b2 = *(const s16x8*)&xm[16 * jb + l16][ks * 32 + quad * 8];
                acc2[jb] = __builtin_amdgcn_mfma_f32_16x16x32_bf16(a2, b2, acc2[jb], 0, 0, 0);
            }
        }

        // epilogue: out = relu(gc + bias + x) ; residual read f32 from x directly
        const int bt = 2 * g2 + pass;
        const int b2i = bt / NT, t2 = bt - NT * b2i;
#pragma unroll
        for (int jb = 0; jb < 4; ++jb) {
            int mm = 16 * jb + l16;
#pragma unroll
            for (int r = 0; r < 4; ++r) {
                int o = 16 * wid + 4 * quad + r;
                size_t idx = (((size_t)(b2i * NC + o) * NT + t2) * NN) + m_base + mm;
                float v = acc2[jb][r] + bo[r] + x[idx];
                out[idx] = fmaxf(v, 0.f);
            }
        }
    }
}

extern "C" void kernel_launch(void* const* d_in, const int* in_sizes, int n_in,
                              void* d_out, int out_size, void* d_ws, size_t ws_size,
                              hipStream_t stream) {
    const float* x     = (const float*)d_in[0];
    const float* kern  = (const float*)d_in[1];
    const float* theta = (const float*)d_in[2];
    const float* bias  = (const float*)d_in[3];
    float* out = (float*)d_out;
    (void)in_sizes; (void)n_in; (void)out_size; (void)ws_size;

    ush* apan = (ush*)((char*)d_ws + APAN_OFF);
    ush* kbp  = (ush*)((char*)d_ws + KB_OFF);
    ush* thbf = (ush*)((char*)d_ws + TH_OFF);

    hipLaunchKernelGGL(spatio_prep, dim3(6576), dim3(256), 0, stream,
                       x, kern, theta, apan, kbp, thbf);
    hipLaunchKernelGGL(spatio_main, dim3(96, 16), dim3(256), 0, stream,
                       apan, kbp, thbf, bias, x, out);
}